// Round 16
// baseline (148.259 us; speedup 1.0000x reference)
//
#include <hip/hip_runtime.h>
#include <hip/hip_bf16.h>

#define NN 50000
#define NE 800000
#define D 128
#define NEG_SLOPE 0.01f
#define LN_EPS 1e-5f

#define NPB 256                 // nodes per bucket (bucket = dst >> 8)
#define NB 196                  // ceil(NN / NPB); NB*256 = 50176
#define CAP 6144                // per-bucket bedge capacity (avg 4082, max ~4340)
#define ECH 8192                // edges per bucket-workgroup
#define NCH ((NE + ECH - 1) / ECH)  // 98
#define NDEG 256                // deg-atomic blocks in fused_a
#define NWPK 128                // wt_pack blocks in fused_a
#define NGEMM ((NN + 63) / 64)  // 782

typedef __attribute__((ext_vector_type(8))) short bf16x8;
typedef __attribute__((ext_vector_type(4))) float f32x4;
typedef __attribute__((ext_vector_type(4))) int i32x4;

// f32 -> bf16 round-to-nearest-even (finite values)
__device__ inline unsigned short f2bf(float f) {
    unsigned u = __float_as_uint(f);
    unsigned r = 0x7FFFu + ((u >> 16) & 1u);
    return (unsigned short)((u + r) >> 16);
}
// unpack one dword = 2 bf16 -> 2 floats
__device__ inline void bf2x(unsigned u, float& lo, float& hi) {
    lo = __uint_as_float(u << 16);
    hi = __uint_as_float(u & 0xFFFF0000u);
}

// ---------------- fused_a: bucket scatter || deg atomics || wt_pack ----------------
// bedge entry packed: src (16 b) | (dst & 255) << 16  -- bucket implicit in region.
__global__ __launch_bounds__(256) void fused_a(const int* __restrict__ src,
                                               const int* __restrict__ dst,
                                               int* __restrict__ bcursor,
                                               unsigned* __restrict__ bedge,
                                               int* __restrict__ deg,
                                               const float* __restrict__ W1,
                                               const float* __restrict__ W2,
                                               unsigned short* __restrict__ WT1,
                                               unsigned short* __restrict__ WT2,
                                               unsigned short* __restrict__ hbf,
                                               unsigned short* __restrict__ hbf2) {
    __shared__ int hist[NB], lcur[NB], gbase[NB];
    int bid = blockIdx.x, t = threadIdx.x;
    if (bid < NCH) {
        int e0 = bid * ECH;
        int ecnt = min(ECH, NE - e0);
        if (t < NB) hist[t] = 0;
        __syncthreads();
        for (int k = t; k < ecnt; k += 256) atomicAdd(&hist[dst[e0 + k] >> 8], 1);
        __syncthreads();
        if (t < NB) {
            gbase[t] = atomicAdd(&bcursor[t], hist[t]);   // reserve exclusive run
            lcur[t] = 0;
        }
        __syncthreads();
        for (int k = t; k < ecnt; k += 256) {
            int s = src[e0 + k], d = dst[e0 + k];
            int b = d >> 8;
            int p = atomicAdd(&lcur[b], 1);
            bedge[(size_t)b * CAP + gbase[b] + p] = (unsigned)s | ((unsigned)(d & 255) << 16);
        }
    } else if (bid < NCH + NDEG) {
        // degree count via global atomics (overlapped with scatter traffic)
        for (int k = (bid - NCH) * 256 + t; k < NE; k += NDEG * 256)
            atomicAdd(&deg[dst[k]], 1);
    } else {
        int tid = (bid - NCH - NDEG) * 256 + t;           // [0, 32768)
        if (tid < 32) {
            uint4 z = make_uint4(0u, 0u, 0u, 0u);
            if (tid < 16) *(uint4*)&hbf[(size_t)NN * D + tid * 8] = z;
            else          *(uint4*)&hbf2[(size_t)NN * D + (tid - 16) * 8] = z;
        }
        const float* W = (tid < D * D) ? W1 : W2;
        unsigned short* WT = (tid < D * D) ? WT1 : WT2;
        int id = tid & (D * D - 1);
        int nn = id & 127, k = id >> 7;
        WT[nn * 128 + k] = f2bf(W[k * 128 + nn]);
    }
}

// ---------------- dinv_rowinfo: deg -> dinv + padded-run allocation (ticket) ----------------
__global__ __launch_bounds__(256) void dinv_rowinfo(const int* __restrict__ deg,
                                                    float* __restrict__ dinv,
                                                    int2* __restrict__ rowinfo,
                                                    int* __restrict__ ticket) {
    __shared__ int tmp[256];
    __shared__ int base;
    int b = blockIdx.x, t = threadIdx.x;
    int node = b * NPB + t;
    int dg = (node < NN) ? deg[node] : 0;
    int pdeg = (dg + 7) & ~7;                     // pad to multiple of 8
    tmp[t] = pdeg;
    __syncthreads();
    for (int off = 1; off < 256; off <<= 1) {
        int uu = (t >= off) ? tmp[t - off] : 0;
        __syncthreads();
        tmp[t] += uu;
        __syncthreads();
    }
    if (t == 255) base = atomicAdd(ticket, tmp[255]);
    __syncthreads();
    if (node < NN) {
        dinv[node] = rsqrtf((float)(dg + 1));     // +1: self-loop
        rowinfo[node] = make_int2(base + tmp[t] - pdeg, pdeg);
    }
}

// ---------------- fused_bg: csr scatter (196 blocks) || GEMM1 (782 blocks) ----------------
struct CsrLDS { int rl[NPB], cur[NPB], pd[NPB]; };
struct GemmLDS {
    unsigned short a[64 * 128];     // 16 KB
    unsigned short w[128 * 128];    // 32 KB
};
union BgLDS { CsrLDS c; GemmLDS g; };

__global__ __launch_bounds__(256) void fused_bg(const unsigned* __restrict__ bedge,
                                                const int* __restrict__ bcnt,
                                                const int2* __restrict__ rowinfo,
                                                int* __restrict__ csr_src,
                                                const float* __restrict__ A,
                                                const unsigned short* __restrict__ WT,
                                                const float* __restrict__ dinv,
                                                unsigned short* __restrict__ out) {
    __shared__ BgLDS u;
    int bid = blockIdx.x, t = threadIdx.x;

    if (bid < NB) {
        // ---- single-pass CSR scatter (deg/rowinfo precomputed) ----
        CsrLDS& L = u.c;
        int b = bid;
        int node = b * NPB + t;
        int2 ri = (node < NN) ? rowinfo[node] : make_int2(0, 0);
        L.rl[t] = ri.x;
        L.pd[t] = ri.y;
        L.cur[t] = 0;
        __syncthreads();
        int s0 = b * CAP, s1 = s0 + bcnt[b];
        for (int k = s0 + t; k < s1; k += 256) {
            unsigned w = bedge[k];
            int li = w >> 16;
            int p = atomicAdd(&L.cur[li], 1);
            csr_src[L.rl[li] + p] = (int)(w & 0xFFFFu);
        }
        __syncthreads();
        int dgc = L.cur[t];
        int pend = L.pd[t];
        for (int k = dgc; k < pend; ++k)
            csr_src[L.rl[t] + k] = NN;            // zero-row pad
    } else {
        // ---- GEMM1: hbf = dinv ⊙ bf16(x @ W1) ----
        GemmLDS& L = u.g;
        int m0 = (bid - NB) * 64;
        #pragma unroll
        for (int it = 0; it < 8; ++it) {
            int idx = it * 256 + t;
            int row = idx >> 4, c = idx & 15;
            uint4 v = *(const uint4*)&WT[row * 128 + c * 8];
            int byte = (row * 256 + c * 16) ^ ((row & 7) << 4);
            *(uint4*)((char*)L.w + byte) = v;
        }
        #pragma unroll
        for (int it = 0; it < 4; ++it) {
            int idx = it * 256 + t;
            int row = idx >> 4, c = idx & 15;
            int grow = m0 + row;
            uint4 w = make_uint4(0u, 0u, 0u, 0u);
            if (grow < NN) {
                float4 v0 = *(const float4*)&A[(size_t)grow * D + c * 8];
                float4 v1 = *(const float4*)&A[(size_t)grow * D + c * 8 + 4];
                w.x = (unsigned)f2bf(v0.x) | ((unsigned)f2bf(v0.y) << 16);
                w.y = (unsigned)f2bf(v0.z) | ((unsigned)f2bf(v0.w) << 16);
                w.z = (unsigned)f2bf(v1.x) | ((unsigned)f2bf(v1.y) << 16);
                w.w = (unsigned)f2bf(v1.z) | ((unsigned)f2bf(v1.w) << 16);
            }
            int byte = (row * 256 + c * 16) ^ ((row & 7) << 4);
            *(uint4*)((char*)L.a + byte) = w;
        }
        __syncthreads();

        int wv = t >> 6, l = t & 63;
        int lrow = l & 15, lgrp = l >> 4;
        int arow = wv * 16 + lrow;

        f32x4 acc[8];
        #pragma unroll
        for (int nf = 0; nf < 8; ++nf) acc[nf] = (f32x4){0.f, 0.f, 0.f, 0.f};

        #pragma unroll
        for (int kk = 0; kk < 4; ++kk) {
            int abyte = (arow * 256 + kk * 64 + lgrp * 16) ^ ((arow & 7) << 4);
            bf16x8 afrag = *(bf16x8*)((char*)L.a + abyte);
            #pragma unroll
            for (int nf = 0; nf < 8; ++nf) {
                int bcol = nf * 16 + lrow;
                int bbyte = (bcol * 256 + kk * 64 + lgrp * 16) ^ ((bcol & 7) << 4);
                bf16x8 bfrag = *(bf16x8*)((char*)L.w + bbyte);
                acc[nf] = __builtin_amdgcn_mfma_f32_16x16x32_bf16(afrag, bfrag, acc[nf], 0, 0, 0);
            }
        }

        #pragma unroll
        for (int r = 0; r < 4; ++r) {
            int grow = m0 + wv * 16 + lgrp * 4 + r;
            if (grow < NN) {
                float dv = dinv[grow];
                #pragma unroll
                for (int nf = 0; nf < 8; ++nf)
                    out[(size_t)grow * D + nf * 16 + lrow] = f2bf(dv * acc[nf][r]);
            }
        }
    }
}

// ---------------- aggregation helpers (coef-free: pure adds) ----------------

__device__ inline void agg8s(const unsigned* __restrict__ h, const int* __restrict__ csr,
                             int e, int lane, float& ax_, float& ay_) {
    i32x4 s0 = __builtin_nontemporal_load((const i32x4*)(csr + e));
    i32x4 s1 = __builtin_nontemporal_load((const i32x4*)(csr + e + 4));
    unsigned g0 = h[(size_t)s0[0] * (D / 2) + lane];
    unsigned g1 = h[(size_t)s0[1] * (D / 2) + lane];
    unsigned g2 = h[(size_t)s0[2] * (D / 2) + lane];
    unsigned g3 = h[(size_t)s0[3] * (D / 2) + lane];
    unsigned g4 = h[(size_t)s1[0] * (D / 2) + lane];
    unsigned g5 = h[(size_t)s1[1] * (D / 2) + lane];
    unsigned g6 = h[(size_t)s1[2] * (D / 2) + lane];
    unsigned g7 = h[(size_t)s1[3] * (D / 2) + lane];
    float lo, hi;
    bf2x(g0, lo, hi); ax_ += lo; ay_ += hi;
    bf2x(g1, lo, hi); ax_ += lo; ay_ += hi;
    bf2x(g2, lo, hi); ax_ += lo; ay_ += hi;
    bf2x(g3, lo, hi); ax_ += lo; ay_ += hi;
    bf2x(g4, lo, hi); ax_ += lo; ay_ += hi;
    bf2x(g5, lo, hi); ax_ += lo; ay_ += hi;
    bf2x(g6, lo, hi); ax_ += lo; ay_ += hi;
    bf2x(g7, lo, hi); ax_ += lo; ay_ += hi;
}

// joint 2-node loop: 16-deep per node (32 gathers in flight), then 8-deep drains
__device__ inline void agg_2node(const unsigned* __restrict__ h,
                                 const int* __restrict__ csr,
                                 int eA, int eA1, int eB, int eB1, int lane,
                                 float& aAx, float& aAy, float& aBx, float& aBy) {
    while (eA + 16 <= eA1 && eB + 16 <= eB1) {
        i32x4 sA0 = __builtin_nontemporal_load((const i32x4*)(csr + eA));
        i32x4 sA1 = __builtin_nontemporal_load((const i32x4*)(csr + eA + 4));
        i32x4 sA2 = __builtin_nontemporal_load((const i32x4*)(csr + eA + 8));
        i32x4 sA3 = __builtin_nontemporal_load((const i32x4*)(csr + eA + 12));
        i32x4 sB0 = __builtin_nontemporal_load((const i32x4*)(csr + eB));
        i32x4 sB1 = __builtin_nontemporal_load((const i32x4*)(csr + eB + 4));
        i32x4 sB2 = __builtin_nontemporal_load((const i32x4*)(csr + eB + 8));
        i32x4 sB3 = __builtin_nontemporal_load((const i32x4*)(csr + eB + 12));
        unsigned gA0 = h[(size_t)sA0[0] * (D / 2) + lane];
        unsigned gA1 = h[(size_t)sA0[1] * (D / 2) + lane];
        unsigned gA2 = h[(size_t)sA0[2] * (D / 2) + lane];
        unsigned gA3 = h[(size_t)sA0[3] * (D / 2) + lane];
        unsigned gA4 = h[(size_t)sA1[0] * (D / 2) + lane];
        unsigned gA5 = h[(size_t)sA1[1] * (D / 2) + lane];
        unsigned gA6 = h[(size_t)sA1[2] * (D / 2) + lane];
        unsigned gA7 = h[(size_t)sA1[3] * (D / 2) + lane];
        unsigned gA8 = h[(size_t)sA2[0] * (D / 2) + lane];
        unsigned gA9 = h[(size_t)sA2[1] * (D / 2) + lane];
        unsigned gAa = h[(size_t)sA2[2] * (D / 2) + lane];
        unsigned gAb = h[(size_t)sA2[3] * (D / 2) + lane];
        unsigned gAc = h[(size_t)sA3[0] * (D / 2) + lane];
        unsigned gAd = h[(size_t)sA3[1] * (D / 2) + lane];
        unsigned gAe = h[(size_t)sA3[2] * (D / 2) + lane];
        unsigned gAf = h[(size_t)sA3[3] * (D / 2) + lane];
        unsigned gB0 = h[(size_t)sB0[0] * (D / 2) + lane];
        unsigned gB1 = h[(size_t)sB0[1] * (D / 2) + lane];
        unsigned gB2 = h[(size_t)sB0[2] * (D / 2) + lane];
        unsigned gB3 = h[(size_t)sB0[3] * (D / 2) + lane];
        unsigned gB4 = h[(size_t)sB1[0] * (D / 2) + lane];
        unsigned gB5 = h[(size_t)sB1[1] * (D / 2) + lane];
        unsigned gB6 = h[(size_t)sB1[2] * (D / 2) + lane];
        unsigned gB7 = h[(size_t)sB1[3] * (D / 2) + lane];
        unsigned gB8 = h[(size_t)sB2[0] * (D / 2) + lane];
        unsigned gB9 = h[(size_t)sB2[1] * (D / 2) + lane];
        unsigned gBa = h[(size_t)sB2[2] * (D / 2) + lane];
        unsigned gBb = h[(size_t)sB2[3] * (D / 2) + lane];
        unsigned gBc = h[(size_t)sB3[0] * (D / 2) + lane];
        unsigned gBd = h[(size_t)sB3[1] * (D / 2) + lane];
        unsigned gBe = h[(size_t)sB3[2] * (D / 2) + lane];
        unsigned gBf = h[(size_t)sB3[3] * (D / 2) + lane];
        float lo, hi;
        bf2x(gA0, lo, hi); aAx += lo; aAy += hi;
        bf2x(gA1, lo, hi); aAx += lo; aAy += hi;
        bf2x(gA2, lo, hi); aAx += lo; aAy += hi;
        bf2x(gA3, lo, hi); aAx += lo; aAy += hi;
        bf2x(gA4, lo, hi); aAx += lo; aAy += hi;
        bf2x(gA5, lo, hi); aAx += lo; aAy += hi;
        bf2x(gA6, lo, hi); aAx += lo; aAy += hi;
        bf2x(gA7, lo, hi); aAx += lo; aAy += hi;
        bf2x(gA8, lo, hi); aAx += lo; aAy += hi;
        bf2x(gA9, lo, hi); aAx += lo; aAy += hi;
        bf2x(gAa, lo, hi); aAx += lo; aAy += hi;
        bf2x(gAb, lo, hi); aAx += lo; aAy += hi;
        bf2x(gAc, lo, hi); aAx += lo; aAy += hi;
        bf2x(gAd, lo, hi); aAx += lo; aAy += hi;
        bf2x(gAe, lo, hi); aAx += lo; aAy += hi;
        bf2x(gAf, lo, hi); aAx += lo; aAy += hi;
        bf2x(gB0, lo, hi); aBx += lo; aBy += hi;
        bf2x(gB1, lo, hi); aBx += lo; aBy += hi;
        bf2x(gB2, lo, hi); aBx += lo; aBy += hi;
        bf2x(gB3, lo, hi); aBx += lo; aBy += hi;
        bf2x(gB4, lo, hi); aBx += lo; aBy += hi;
        bf2x(gB5, lo, hi); aBx += lo; aBy += hi;
        bf2x(gB6, lo, hi); aBx += lo; aBy += hi;
        bf2x(gB7, lo, hi); aBx += lo; aBy += hi;
        bf2x(gB8, lo, hi); aBx += lo; aBy += hi;
        bf2x(gB9, lo, hi); aBx += lo; aBy += hi;
        bf2x(gBa, lo, hi); aBx += lo; aBy += hi;
        bf2x(gBb, lo, hi); aBx += lo; aBy += hi;
        bf2x(gBc, lo, hi); aBx += lo; aBy += hi;
        bf2x(gBd, lo, hi); aBx += lo; aBy += hi;
        bf2x(gBe, lo, hi); aBx += lo; aBy += hi;
        bf2x(gBf, lo, hi); aBx += lo; aBy += hi;
        eA += 16; eB += 16;
    }
    while (eA + 8 <= eA1 && eB + 8 <= eB1) {
        agg8s(h, csr, eA, lane, aAx, aAy);
        agg8s(h, csr, eB, lane, aBx, aBy);
        eA += 8; eB += 8;
    }
    while (eA < eA1) { agg8s(h, csr, eA, lane, aAx, aAy); eA += 8; }
    while (eB < eB1) { agg8s(h, csr, eB, lane, aBx, aBy); eB += 8; }
}

// ---------------- layer 1: agg + bias + leaky + residual + LN1 + GEMM2 (fused MFMA) ----------------
__global__ __launch_bounds__(512) void agg_ln1_gemm(const unsigned* __restrict__ h,
                                                    const float* __restrict__ x,
                                                    const float* __restrict__ bias,
                                                    const float* __restrict__ gamma,
                                                    const float* __restrict__ beta,
                                                    const float* __restrict__ dinv,
                                                    const int2* __restrict__ rowinfo,
                                                    const int* __restrict__ csr_src,
                                                    const unsigned short* __restrict__ wt2,
                                                    unsigned short* __restrict__ hbf2) {
    __shared__ __align__(16) unsigned short w_lds[128 * 128];  // 32 KB
    __shared__ __align__(16) unsigned short a_lds[16 * 128];   // 4 KB
    int t = threadIdx.x;

    #pragma unroll
    for (int it = 0; it < 4; ++it) {
        int idx = it * 512 + t;
        int row = idx >> 4, c = idx & 15;
        uint4 v = *(const uint4*)&wt2[row * 128 + c * 8];
        int byte = (row * 256 + c * 16) ^ ((row & 7) << 4);
        *(uint4*)((char*)w_lds + byte) = v;
    }

    int wid = t >> 6, lane = t & 63;
    int iA = blockIdx.x * 16 + wid * 2;   // NN = 50000 = 3125 * 16, exact
    int iB = iA + 1;
    float diA = dinv[iA], diB = dinv[iB];

    float aAx, aAy, aBx, aBy;
    bf2x(h[(size_t)iA * (D / 2) + lane], aAx, aAy);
    bf2x(h[(size_t)iB * (D / 2) + lane], aBx, aBy);

    int2 riA = rowinfo[iA];
    int2 riB = rowinfo[iB];
    int eA = __builtin_amdgcn_readfirstlane(riA.x);
    int eA1 = eA + __builtin_amdgcn_readfirstlane(riA.y);
    int eB = __builtin_amdgcn_readfirstlane(riB.x);
    int eB1 = eB + __builtin_amdgcn_readfirstlane(riB.y);
    agg_2node(h, csr_src, eA, eA1, eB, eB1, lane, aAx, aAy, aBx, aBy);

    float2 bv = *(const float2*)&bias[2 * lane];
    float2 gv = *(const float2*)&gamma[2 * lane];
    float2 bt = *(const float2*)&beta[2 * lane];

    aAx = fmaf(diA, aAx, bv.x); aAy = fmaf(diA, aAy, bv.y);
    aBx = fmaf(diB, aBx, bv.x); aBy = fmaf(diB, aBy, bv.y);
    aAx = aAx > 0.f ? aAx : NEG_SLOPE * aAx;
    aAy = aAy > 0.f ? aAy : NEG_SLOPE * aAy;
    aBx = aBx > 0.f ? aBx : NEG_SLOPE * aBx;
    aBy = aBy > 0.f ? aBy : NEG_SLOPE * aBy;

    size_t rowA = (size_t)iA * D + 2 * lane;
    size_t rowB = (size_t)iB * D + 2 * lane;
    float2 xA = *(const float2*)&x[rowA];
    float2 xB = *(const float2*)&x[rowB];
    float vA0 = aAx + xA.x, vA1 = aAy + xA.y;
    float vB0 = aBx + xB.x, vB1 = aBy + xB.y;

    float sA1 = vA0 + vA1, sA2 = vA0 * vA0 + vA1 * vA1;
    float sB1 = vB0 + vB1, sB2 = vB0 * vB0 + vB1 * vB1;
    #pragma unroll
    for (int off = 1; off < 64; off <<= 1) {
        sA1 += __shfl_xor(sA1, off, 64);
        sA2 += __shfl_xor(sA2, off, 64);
        sB1 += __shfl_xor(sB1, off, 64);
        sB2 += __shfl_xor(sB2, off, 64);
    }
    float muA = sA1 * (1.f / 128.f);
    float varA = fmaxf(sA2 * (1.f / 128.f) - muA * muA, 0.f);
    float rsA = rsqrtf(varA + LN_EPS);
    float muB = sB1 * (1.f / 128.f);
    float varB = fmaxf(sB2 * (1.f / 128.f) - muB * muB, 0.f);
    float rsB = rsqrtf(varB + LN_EPS);

    float oA0 = (vA0 - muA) * rsA * gv.x + bt.x;
    float oA1 = (vA1 - muA) * rsA * gv.y + bt.y;
    float oB0 = (vB0 - muB) * rsB * gv.x + bt.x;
    float oB1 = (vB1 - muB) * rsB * gv.y + bt.y;

    int rA = wid * 2, rB = wid * 2 + 1;
    unsigned dwA = (unsigned)f2bf(oA0) | ((unsigned)f2bf(oA1) << 16);
    unsigned dwB = (unsigned)f2bf(oB0) | ((unsigned)f2bf(oB1) << 16);
    int byteA = (rA * 256 + lane * 4) ^ ((rA & 7) << 4);
    int byteB = (rB * 256 + lane * 4) ^ ((rB & 7) << 4);
    *(unsigned*)((char*)a_lds + byteA) = dwA;
    *(unsigned*)((char*)a_lds + byteB) = dwB;
    __syncthreads();

    int lrow = lane & 15, lgrp = lane >> 4;
    f32x4 acc = (f32x4){0.f, 0.f, 0.f, 0.f};
    #pragma unroll
    for (int kk = 0; kk < 4; ++kk) {
        int abyte = (lrow * 256 + kk * 64 + lgrp * 16) ^ ((lrow & 7) << 4);
        bf16x8 afrag = *(bf16x8*)((char*)a_lds + abyte);
        int bcol = wid * 16 + lrow;
        int bbyte = (bcol * 256 + kk * 64 + lgrp * 16) ^ ((bcol & 7) << 4);
        bf16x8 bfrag = *(bf16x8*)((char*)w_lds + bbyte);
        acc = __builtin_amdgcn_mfma_f32_16x16x32_bf16(afrag, bfrag, acc, 0, 0, 0);
    }
    #pragma unroll
    for (int r = 0; r < 4; ++r) {
        int grow = blockIdx.x * 16 + lgrp * 4 + r;
        hbf2[(size_t)grow * D + wid * 16 + lrow] = f2bf(dinv[grow] * acc[r]);
    }
}

// ---------------- layer 2: agg + bias + residual + LN2 + leaky (final f32 out) ----------------
__global__ __launch_bounds__(256) void agg_ln2(const unsigned* __restrict__ h,
                                               const float* __restrict__ x,
                                               const float* __restrict__ bias,
                                               const float* __restrict__ gamma,
                                               const float* __restrict__ beta,
                                               const float* __restrict__ dinv,
                                               const int2* __restrict__ rowinfo,
                                               const int* __restrict__ csr_src,
                                               float* __restrict__ out) {
    int wid = threadIdx.x >> 6;
    int lane = threadIdx.x & 63;
    int iA = blockIdx.x * 8 + wid * 2;   // NN = 50000 = 6250 * 8, exact
    int iB = iA + 1;
    float diA = dinv[iA], diB = dinv[iB];

    float aAx, aAy, aBx, aBy;
    bf2x(h[(size_t)iA * (D / 2) + lane], aAx, aAy);
    bf2x(h[(size_t)iB * (D / 2) + lane], aBx, aBy);

    int2 riA = rowinfo[iA];
    int2 riB = rowinfo[iB];
    int eA = __builtin_amdgcn_readfirstlane(riA.x);
    int eA1 = eA + __builtin_amdgcn_readfirstlane(riA.y);
    int eB = __builtin_amdgcn_readfirstlane(riB.x);
    int eB1 = eB + __builtin_amdgcn_readfirstlane(riB.y);
    agg_2node(h, csr_src, eA, eA1, eB, eB1, lane, aAx, aAy, aBx, aBy);

    float2 bv = *(const float2*)&bias[2 * lane];
    float2 gv = *(const float2*)&gamma[2 * lane];
    float2 bt = *(const float2*)&beta[2 * lane];

    aAx = fmaf(diA, aAx, bv.x); aAy = fmaf(diA, aAy, bv.y);
    aBx = fmaf(diB, aBx, bv.x); aBy = fmaf(diB, aBy, bv.y);
    size_t rowA = (size_t)iA * D + 2 * lane;
    size_t rowB = (size_t)iB * D + 2 * lane;
    float2 xA = *(const float2*)&x[rowA];
    float2 xB = *(const float2*)&x[rowB];
    float vA0 = aAx + xA.x, vA1 = aAy + xA.y;
    float vB0 = aBx + xB.x, vB1 = aBy + xB.y;

    float sA1 = vA0 + vA1, sA2 = vA0 * vA0 + vA1 * vA1;
    float sB1 = vB0 + vB1, sB2 = vB0 * vB0 + vB1 * vB1;
    #pragma unroll
    for (int off = 1; off < 64; off <<= 1) {
        sA1 += __shfl_xor(sA1, off, 64);
        sA2 += __shfl_xor(sA2, off, 64);
        sB1 += __shfl_xor(sB1, off, 64);
        sB2 += __shfl_xor(sB2, off, 64);
    }
    float muA = sA1 * (1.f / 128.f);
    float varA = fmaxf(sA2 * (1.f / 128.f) - muA * muA, 0.f);
    float rsA = rsqrtf(varA + LN_EPS);
    float muB = sB1 * (1.f / 128.f);
    float varB = fmaxf(sB2 * (1.f / 128.f) - muB * muB, 0.f);
    float rsB = rsqrtf(varB + LN_EPS);

    float oA0 = (vA0 - muA) * rsA * gv.x + bt.x;
    float oA1 = (vA1 - muA) * rsA * gv.y + bt.y;
    float oB0 = (vB0 - muB) * rsB * gv.x + bt.x;
    float oB1 = (vB1 - muB) * rsB * gv.y + bt.y;
    oA0 = oA0 > 0.f ? oA0 : NEG_SLOPE * oA0;
    oA1 = oA1 > 0.f ? oA1 : NEG_SLOPE * oA1;
    oB0 = oB0 > 0.f ? oB0 : NEG_SLOPE * oB0;
    oB1 = oB1 > 0.f ? oB1 : NEG_SLOPE * oB1;
    *(float2*)&out[rowA] = make_float2(oA0, oA1);
    *(float2*)&out[rowB] = make_float2(oB0, oB1);
}

extern "C" void kernel_launch(void* const* d_in, const int* in_sizes, int n_in,
                              void* d_out, int out_size, void* d_ws, size_t ws_size,
                              hipStream_t stream) {
    const float* x    = (const float*)d_in[0];
    const int*   ei   = (const int*)d_in[1];   // [2, NE]: row0 src, row1 dst
    const float* W1   = (const float*)d_in[2];
    const float* b1   = (const float*)d_in[3];
    const float* ln1g = (const float*)d_in[4];
    const float* ln1b = (const float*)d_in[5];
    const float* W2   = (const float*)d_in[6];
    const float* b2   = (const float*)d_in[7];
    const float* ln2g = (const float*)d_in[8];
    const float* ln2b = (const float*)d_in[9];
    float* out = (float*)d_out;

    const int* srcp = ei;
    const int* dstp = ei + NE;

    char* ws = (char*)d_ws;
    size_t p = 0;
    auto alloc = [&](size_t bytes) {
        char* r = ws + p;
        p += (bytes + 255) & ~(size_t)255;
        return r;
    };
    // deg + bcursor/ticket adjacent -> single memset
    int*      deg      = (int*)alloc(NN * 4);
    int*      bcursor  = (int*)alloc((NB + 1) * 4);      // [NB] = ticket
    int2*     rowinfo  = (int2*)alloc((size_t)NN * 8);
    float*    dinv     = (float*)alloc(NN * 4);
    unsigned* bedge    = (unsigned*)alloc((size_t)NB * CAP * 4);   // packed 4 B/edge
    int*      csr_src  = (int*)alloc(((size_t)NE + 8 * NN) * 4);   // padded CSR, 4 B/edge
    unsigned short* hbf  = (unsigned short*)alloc((size_t)(NN + 8) * D * 2);  // +zero row
    unsigned short* hbf2 = (unsigned short*)alloc((size_t)(NN + 8) * D * 2);  // +zero row
    unsigned short* wt1  = (unsigned short*)alloc(D * D * 2);
    unsigned short* wt2  = (unsigned short*)alloc(D * D * 2);

    size_t zbytes = (char*)rowinfo - (char*)deg;         // deg + bcursor region
    hipMemsetAsync(deg, 0, zbytes, stream);

    // bucket scatter || deg atomics || weight pack (+ zero pad rows)
    fused_a<<<NCH + NDEG + NWPK, 256, 0, stream>>>(srcp, dstp, bcursor, bedge, deg,
                                                   W1, W2, wt1, wt2, hbf, hbf2);

    // deg -> dinv + padded rowinfo (ticket)
    dinv_rowinfo<<<NB, 256, 0, stream>>>(deg, dinv, rowinfo, &bcursor[NB]);

    // CSR scatter (196 blocks) || GEMM1 (782 blocks)
    fused_bg<<<NB + NGEMM, 256, 0, stream>>>(bedge, bcursor, rowinfo, csr_src,
                                             x, wt1, dinv, hbf);

    // Layer 1 (+ fused GEMM2): hbf2 = dinv ⊙ ( LN1(leaky(agg(hbf)+b1)+x) @ W2 )
    agg_ln1_gemm<<<NN / 16, 512, 0, stream>>>((const unsigned*)hbf, x, b1, ln1g, ln1b,
                                              dinv, rowinfo, csr_src, wt2, hbf2);

    // Layer 2: out = leaky(LN2(agg(hbf2)+b2+x))
    agg_ln2<<<NN / 8, 256, 0, stream>>>((const unsigned*)hbf2, x, b2, ln2g, ln2b,
                                        dinv, rowinfo, csr_src, out);
}

// Round 17
// 124.566 us; speedup vs baseline: 1.1902x; 1.1902x over previous
//
#include <hip/hip_runtime.h>
#include <hip/hip_bf16.h>

#define NN 50000
#define NE 800000
#define D 128
#define NEG_SLOPE 0.01f
#define LN_EPS 1e-5f

#define NPB 256                 // nodes per bucket (bucket = dst >> 8)
#define NB 196                  // ceil(NN / NPB); NB*256 = 50176
#define CAP 6144                // per-bucket bedge capacity (avg 4082, max ~4340)
#define ECH 8192                // edges per bucket-workgroup
#define NCH ((NE + ECH - 1) / ECH)  // 98
#define NWPK 128                // wt_pack blocks appended to fused_a

typedef __attribute__((ext_vector_type(8))) short bf16x8;
typedef __attribute__((ext_vector_type(4))) float f32x4;
typedef __attribute__((ext_vector_type(4))) int i32x4;

// f32 -> bf16 round-to-nearest-even (finite values)
__device__ inline unsigned short f2bf(float f) {
    unsigned u = __float_as_uint(f);
    unsigned r = 0x7FFFu + ((u >> 16) & 1u);
    return (unsigned short)((u + r) >> 16);
}
// unpack one dword = 2 bf16 -> 2 floats
__device__ inline void bf2x(unsigned u, float& lo, float& hi) {
    lo = __uint_as_float(u << 16);
    hi = __uint_as_float(u & 0xFFFF0000u);
}

// ---------------- fused_a: bucket scatter (98 blocks) || wt_pack (128 blocks) ----------------
__global__ __launch_bounds__(256) void fused_a(const int* __restrict__ src,
                                               const int* __restrict__ dst,
                                               int* __restrict__ bcursor,
                                               int2* __restrict__ bedge,
                                               const float* __restrict__ W1,
                                               const float* __restrict__ W2,
                                               unsigned short* __restrict__ WT1,
                                               unsigned short* __restrict__ WT2,
                                               unsigned short* __restrict__ hbf,
                                               unsigned short* __restrict__ hbf2) {
    __shared__ int hist[NB], lcur[NB], gbase[NB];
    int bid = blockIdx.x, t = threadIdx.x;
    if (bid < NCH) {
        int e0 = bid * ECH;
        int ecnt = min(ECH, NE - e0);
        if (t < NB) hist[t] = 0;
        __syncthreads();
        for (int k = t; k < ecnt; k += 256) atomicAdd(&hist[dst[e0 + k] >> 8], 1);
        __syncthreads();
        if (t < NB) {
            gbase[t] = atomicAdd(&bcursor[t], hist[t]);   // reserve exclusive run
            lcur[t] = 0;
        }
        __syncthreads();
        for (int k = t; k < ecnt; k += 256) {
            int s = src[e0 + k], d = dst[e0 + k];
            int b = d >> 8;
            int p = atomicAdd(&lcur[b], 1);
            bedge[(size_t)b * CAP + gbase[b] + p] = make_int2(s, d);
        }
    } else {
        int tid = (bid - NCH) * 256 + t;                  // [0, 32768)
        if (tid < 32) {
            uint4 z = make_uint4(0u, 0u, 0u, 0u);
            if (tid < 16) *(uint4*)&hbf[(size_t)NN * D + tid * 8] = z;
            else          *(uint4*)&hbf2[(size_t)NN * D + (tid - 16) * 8] = z;
        }
        const float* W = (tid < D * D) ? W1 : W2;
        unsigned short* WT = (tid < D * D) ? WT1 : WT2;
        int id = tid & (D * D - 1);
        int nn = id & 127, k = id >> 7;
        WT[nn * 128 + k] = f2bf(W[k * 128 + nn]);
    }
}

// ---------------- fused_b: per-bucket histogram -> dinv/rowinfo -> padded CSR scatter ----------------
__global__ __launch_bounds__(256) void fused_b(const int2* __restrict__ bedge,
                                               const int* __restrict__ bcnt,
                                               float* __restrict__ dinv,
                                               int2* __restrict__ rowinfo,
                                               int* __restrict__ ticket,
                                               int* __restrict__ csr_src) {
    __shared__ int h[NPB];
    __shared__ int tmp[256];
    __shared__ int rl[NPB], cur[NPB];
    __shared__ int base;
    int b = blockIdx.x, t = threadIdx.x;
    h[t] = 0;
    __syncthreads();
    int s0 = b * CAP, s1 = s0 + bcnt[b];
    for (int k = s0 + t; k < s1; k += 256) atomicAdd(&h[bedge[k].y & 255], 1);
    __syncthreads();
    int deg = h[t];
    int node = b * NPB + t;
    int pdeg = (deg + 7) & ~7;                    // pad to multiple of 8
    tmp[t] = pdeg;
    __syncthreads();
    for (int off = 1; off < 256; off <<= 1) {
        int uu = (t >= off) ? tmp[t - off] : 0;
        __syncthreads();
        tmp[t] += uu;
        __syncthreads();
    }
    if (t == 255) base = atomicAdd(ticket, tmp[255]);
    __syncthreads();
    int start = base + tmp[t] - pdeg;
    rl[t] = start;
    cur[t] = 0;
    if (node < NN) {
        dinv[node] = rsqrtf((float)(deg + 1));    // +1: self-loop
        rowinfo[node] = make_int2(start, pdeg);
    }
    __syncthreads();
    for (int k = s0 + t; k < s1; k += 256) {      // bedge slice L2-hot from pass 1
        int2 eg = bedge[k];
        int li = eg.y & 255;
        int p = atomicAdd(&cur[li], 1);
        csr_src[rl[li] + p] = eg.x;
    }
    __syncthreads();
    int dgc = cur[t];
    int pend = (dgc + 7) & ~7;
    for (int k = dgc; k < pend; ++k)
        csr_src[rl[t] + k] = NN;                  // zero-row pad
}

// ---------------- MFMA GEMM1: hbf = bf16( dinv ⊙ (x @ W1) ) ----------------
__global__ __launch_bounds__(256) void gemm_mfma(const float* __restrict__ A,
                                                 const unsigned short* __restrict__ WT,
                                                 const float* __restrict__ dinv,
                                                 unsigned short* __restrict__ out, int n) {
    __shared__ __align__(16) unsigned short a_lds[64 * 128];   // 16 KB
    __shared__ __align__(16) unsigned short w_lds[128 * 128];  // 32 KB
    int t = threadIdx.x;
    int m0 = blockIdx.x * 64;

    #pragma unroll
    for (int it = 0; it < 8; ++it) {
        int idx = it * 256 + t;
        int row = idx >> 4, c = idx & 15;
        uint4 v = *(const uint4*)&WT[row * 128 + c * 8];
        int byte = (row * 256 + c * 16) ^ ((row & 7) << 4);
        *(uint4*)((char*)w_lds + byte) = v;
    }
    #pragma unroll
    for (int it = 0; it < 4; ++it) {
        int idx = it * 256 + t;
        int row = idx >> 4, c = idx & 15;
        int grow = m0 + row;
        uint4 w = make_uint4(0u, 0u, 0u, 0u);
        if (grow < n) {
            float4 v0 = *(const float4*)&A[(size_t)grow * D + c * 8];
            float4 v1 = *(const float4*)&A[(size_t)grow * D + c * 8 + 4];
            w.x = (unsigned)f2bf(v0.x) | ((unsigned)f2bf(v0.y) << 16);
            w.y = (unsigned)f2bf(v0.z) | ((unsigned)f2bf(v0.w) << 16);
            w.z = (unsigned)f2bf(v1.x) | ((unsigned)f2bf(v1.y) << 16);
            w.w = (unsigned)f2bf(v1.z) | ((unsigned)f2bf(v1.w) << 16);
        }
        int byte = (row * 256 + c * 16) ^ ((row & 7) << 4);
        *(uint4*)((char*)a_lds + byte) = w;
    }
    __syncthreads();

    int wv = t >> 6, l = t & 63;
    int lrow = l & 15, lgrp = l >> 4;
    int arow = wv * 16 + lrow;

    f32x4 acc[8];
    #pragma unroll
    for (int nf = 0; nf < 8; ++nf) acc[nf] = (f32x4){0.f, 0.f, 0.f, 0.f};

    #pragma unroll
    for (int kk = 0; kk < 4; ++kk) {
        int abyte = (arow * 256 + kk * 64 + lgrp * 16) ^ ((arow & 7) << 4);
        bf16x8 afrag = *(bf16x8*)((char*)a_lds + abyte);
        #pragma unroll
        for (int nf = 0; nf < 8; ++nf) {
            int bcol = nf * 16 + lrow;
            int bbyte = (bcol * 256 + kk * 64 + lgrp * 16) ^ ((bcol & 7) << 4);
            bf16x8 bfrag = *(bf16x8*)((char*)w_lds + bbyte);
            acc[nf] = __builtin_amdgcn_mfma_f32_16x16x32_bf16(afrag, bfrag, acc[nf], 0, 0, 0);
        }
    }

    #pragma unroll
    for (int r = 0; r < 4; ++r) {
        int grow = m0 + wv * 16 + lgrp * 4 + r;
        if (grow < n) {
            float dv = dinv[grow];
            #pragma unroll
            for (int nf = 0; nf < 8; ++nf)
                out[(size_t)grow * D + nf * 16 + lrow] = f2bf(dv * acc[nf][r]);
        }
    }
}

// ---------------- aggregation helpers (coef-free: pure adds) ----------------

__device__ inline void agg8s(const unsigned* __restrict__ h, const int* __restrict__ csr,
                             int e, int lane, float& ax_, float& ay_) {
    i32x4 s0 = __builtin_nontemporal_load((const i32x4*)(csr + e));
    i32x4 s1 = __builtin_nontemporal_load((const i32x4*)(csr + e + 4));
    unsigned g0 = h[(size_t)s0[0] * (D / 2) + lane];
    unsigned g1 = h[(size_t)s0[1] * (D / 2) + lane];
    unsigned g2 = h[(size_t)s0[2] * (D / 2) + lane];
    unsigned g3 = h[(size_t)s0[3] * (D / 2) + lane];
    unsigned g4 = h[(size_t)s1[0] * (D / 2) + lane];
    unsigned g5 = h[(size_t)s1[1] * (D / 2) + lane];
    unsigned g6 = h[(size_t)s1[2] * (D / 2) + lane];
    unsigned g7 = h[(size_t)s1[3] * (D / 2) + lane];
    float lo, hi;
    bf2x(g0, lo, hi); ax_ += lo; ay_ += hi;
    bf2x(g1, lo, hi); ax_ += lo; ay_ += hi;
    bf2x(g2, lo, hi); ax_ += lo; ay_ += hi;
    bf2x(g3, lo, hi); ax_ += lo; ay_ += hi;
    bf2x(g4, lo, hi); ax_ += lo; ay_ += hi;
    bf2x(g5, lo, hi); ax_ += lo; ay_ += hi;
    bf2x(g6, lo, hi); ax_ += lo; ay_ += hi;
    bf2x(g7, lo, hi); ax_ += lo; ay_ += hi;
}

// joint 2-node loop: 16-deep per node (32 gathers in flight), then 8-deep drains
__device__ inline void agg_2node(const unsigned* __restrict__ h,
                                 const int* __restrict__ csr,
                                 int eA, int eA1, int eB, int eB1, int lane,
                                 float& aAx, float& aAy, float& aBx, float& aBy) {
    while (eA + 16 <= eA1 && eB + 16 <= eB1) {
        i32x4 sA0 = __builtin_nontemporal_load((const i32x4*)(csr + eA));
        i32x4 sA1 = __builtin_nontemporal_load((const i32x4*)(csr + eA + 4));
        i32x4 sA2 = __builtin_nontemporal_load((const i32x4*)(csr + eA + 8));
        i32x4 sA3 = __builtin_nontemporal_load((const i32x4*)(csr + eA + 12));
        i32x4 sB0 = __builtin_nontemporal_load((const i32x4*)(csr + eB));
        i32x4 sB1 = __builtin_nontemporal_load((const i32x4*)(csr + eB + 4));
        i32x4 sB2 = __builtin_nontemporal_load((const i32x4*)(csr + eB + 8));
        i32x4 sB3 = __builtin_nontemporal_load((const i32x4*)(csr + eB + 12));
        unsigned gA0 = h[(size_t)sA0[0] * (D / 2) + lane];
        unsigned gA1 = h[(size_t)sA0[1] * (D / 2) + lane];
        unsigned gA2 = h[(size_t)sA0[2] * (D / 2) + lane];
        unsigned gA3 = h[(size_t)sA0[3] * (D / 2) + lane];
        unsigned gA4 = h[(size_t)sA1[0] * (D / 2) + lane];
        unsigned gA5 = h[(size_t)sA1[1] * (D / 2) + lane];
        unsigned gA6 = h[(size_t)sA1[2] * (D / 2) + lane];
        unsigned gA7 = h[(size_t)sA1[3] * (D / 2) + lane];
        unsigned gA8 = h[(size_t)sA2[0] * (D / 2) + lane];
        unsigned gA9 = h[(size_t)sA2[1] * (D / 2) + lane];
        unsigned gAa = h[(size_t)sA2[2] * (D / 2) + lane];
        unsigned gAb = h[(size_t)sA2[3] * (D / 2) + lane];
        unsigned gAc = h[(size_t)sA3[0] * (D / 2) + lane];
        unsigned gAd = h[(size_t)sA3[1] * (D / 2) + lane];
        unsigned gAe = h[(size_t)sA3[2] * (D / 2) + lane];
        unsigned gAf = h[(size_t)sA3[3] * (D / 2) + lane];
        unsigned gB0 = h[(size_t)sB0[0] * (D / 2) + lane];
        unsigned gB1 = h[(size_t)sB0[1] * (D / 2) + lane];
        unsigned gB2 = h[(size_t)sB0[2] * (D / 2) + lane];
        unsigned gB3 = h[(size_t)sB0[3] * (D / 2) + lane];
        unsigned gB4 = h[(size_t)sB1[0] * (D / 2) + lane];
        unsigned gB5 = h[(size_t)sB1[1] * (D / 2) + lane];
        unsigned gB6 = h[(size_t)sB1[2] * (D / 2) + lane];
        unsigned gB7 = h[(size_t)sB1[3] * (D / 2) + lane];
        unsigned gB8 = h[(size_t)sB2[0] * (D / 2) + lane];
        unsigned gB9 = h[(size_t)sB2[1] * (D / 2) + lane];
        unsigned gBa = h[(size_t)sB2[2] * (D / 2) + lane];
        unsigned gBb = h[(size_t)sB2[3] * (D / 2) + lane];
        unsigned gBc = h[(size_t)sB3[0] * (D / 2) + lane];
        unsigned gBd = h[(size_t)sB3[1] * (D / 2) + lane];
        unsigned gBe = h[(size_t)sB3[2] * (D / 2) + lane];
        unsigned gBf = h[(size_t)sB3[3] * (D / 2) + lane];
        float lo, hi;
        bf2x(gA0, lo, hi); aAx += lo; aAy += hi;
        bf2x(gA1, lo, hi); aAx += lo; aAy += hi;
        bf2x(gA2, lo, hi); aAx += lo; aAy += hi;
        bf2x(gA3, lo, hi); aAx += lo; aAy += hi;
        bf2x(gA4, lo, hi); aAx += lo; aAy += hi;
        bf2x(gA5, lo, hi); aAx += lo; aAy += hi;
        bf2x(gA6, lo, hi); aAx += lo; aAy += hi;
        bf2x(gA7, lo, hi); aAx += lo; aAy += hi;
        bf2x(gA8, lo, hi); aAx += lo; aAy += hi;
        bf2x(gA9, lo, hi); aAx += lo; aAy += hi;
        bf2x(gAa, lo, hi); aAx += lo; aAy += hi;
        bf2x(gAb, lo, hi); aAx += lo; aAy += hi;
        bf2x(gAc, lo, hi); aAx += lo; aAy += hi;
        bf2x(gAd, lo, hi); aAx += lo; aAy += hi;
        bf2x(gAe, lo, hi); aAx += lo; aAy += hi;
        bf2x(gAf, lo, hi); aAx += lo; aAy += hi;
        bf2x(gB0, lo, hi); aBx += lo; aBy += hi;
        bf2x(gB1, lo, hi); aBx += lo; aBy += hi;
        bf2x(gB2, lo, hi); aBx += lo; aBy += hi;
        bf2x(gB3, lo, hi); aBx += lo; aBy += hi;
        bf2x(gB4, lo, hi); aBx += lo; aBy += hi;
        bf2x(gB5, lo, hi); aBx += lo; aBy += hi;
        bf2x(gB6, lo, hi); aBx += lo; aBy += hi;
        bf2x(gB7, lo, hi); aBx += lo; aBy += hi;
        bf2x(gB8, lo, hi); aBx += lo; aBy += hi;
        bf2x(gB9, lo, hi); aBx += lo; aBy += hi;
        bf2x(gBa, lo, hi); aBx += lo; aBy += hi;
        bf2x(gBb, lo, hi); aBx += lo; aBy += hi;
        bf2x(gBc, lo, hi); aBx += lo; aBy += hi;
        bf2x(gBd, lo, hi); aBx += lo; aBy += hi;
        bf2x(gBe, lo, hi); aBx += lo; aBy += hi;
        bf2x(gBf, lo, hi); aBx += lo; aBy += hi;
        eA += 16; eB += 16;
    }
    while (eA + 8 <= eA1 && eB + 8 <= eB1) {
        agg8s(h, csr, eA, lane, aAx, aAy);
        agg8s(h, csr, eB, lane, aBx, aBy);
        eA += 8; eB += 8;
    }
    while (eA < eA1) { agg8s(h, csr, eA, lane, aAx, aAy); eA += 8; }
    while (eB < eB1) { agg8s(h, csr, eB, lane, aBx, aBy); eB += 8; }
}

// ---------------- layer 1: agg + bias + leaky + residual + LN1 + GEMM2 (fused MFMA) ----------------
__global__ __launch_bounds__(512) void agg_ln1_gemm(const unsigned* __restrict__ h,
                                                    const float* __restrict__ x,
                                                    const float* __restrict__ bias,
                                                    const float* __restrict__ gamma,
                                                    const float* __restrict__ beta,
                                                    const float* __restrict__ dinv,
                                                    const int2* __restrict__ rowinfo,
                                                    const int* __restrict__ csr_src,
                                                    const unsigned short* __restrict__ wt2,
                                                    unsigned short* __restrict__ hbf2) {
    __shared__ __align__(16) unsigned short w_lds[128 * 128];  // 32 KB
    __shared__ __align__(16) unsigned short a_lds[16 * 128];   // 4 KB
    int t = threadIdx.x;

    #pragma unroll
    for (int it = 0; it < 4; ++it) {
        int idx = it * 512 + t;
        int row = idx >> 4, c = idx & 15;
        uint4 v = *(const uint4*)&wt2[row * 128 + c * 8];
        int byte = (row * 256 + c * 16) ^ ((row & 7) << 4);
        *(uint4*)((char*)w_lds + byte) = v;
    }

    int wid = t >> 6, lane = t & 63;
    int iA = blockIdx.x * 16 + wid * 2;   // NN = 50000 = 3125 * 16, exact
    int iB = iA + 1;
    float diA = dinv[iA], diB = dinv[iB];

    float aAx, aAy, aBx, aBy;
    bf2x(h[(size_t)iA * (D / 2) + lane], aAx, aAy);
    bf2x(h[(size_t)iB * (D / 2) + lane], aBx, aBy);

    int2 riA = rowinfo[iA];
    int2 riB = rowinfo[iB];
    int eA = __builtin_amdgcn_readfirstlane(riA.x);
    int eA1 = eA + __builtin_amdgcn_readfirstlane(riA.y);
    int eB = __builtin_amdgcn_readfirstlane(riB.x);
    int eB1 = eB + __builtin_amdgcn_readfirstlane(riB.y);
    agg_2node(h, csr_src, eA, eA1, eB, eB1, lane, aAx, aAy, aBx, aBy);

    float2 bv = *(const float2*)&bias[2 * lane];
    float2 gv = *(const float2*)&gamma[2 * lane];
    float2 bt = *(const float2*)&beta[2 * lane];

    aAx = fmaf(diA, aAx, bv.x); aAy = fmaf(diA, aAy, bv.y);
    aBx = fmaf(diB, aBx, bv.x); aBy = fmaf(diB, aBy, bv.y);
    aAx = aAx > 0.f ? aAx : NEG_SLOPE * aAx;
    aAy = aAy > 0.f ? aAy : NEG_SLOPE * aAy;
    aBx = aBx > 0.f ? aBx : NEG_SLOPE * aBx;
    aBy = aBy > 0.f ? aBy : NEG_SLOPE * aBy;

    size_t rowA = (size_t)iA * D + 2 * lane;
    size_t rowB = (size_t)iB * D + 2 * lane;
    float2 xA = *(const float2*)&x[rowA];
    float2 xB = *(const float2*)&x[rowB];
    float vA0 = aAx + xA.x, vA1 = aAy + xA.y;
    float vB0 = aBx + xB.x, vB1 = aBy + xB.y;

    float sA1 = vA0 + vA1, sA2 = vA0 * vA0 + vA1 * vA1;
    float sB1 = vB0 + vB1, sB2 = vB0 * vB0 + vB1 * vB1;
    #pragma unroll
    for (int off = 1; off < 64; off <<= 1) {
        sA1 += __shfl_xor(sA1, off, 64);
        sA2 += __shfl_xor(sA2, off, 64);
        sB1 += __shfl_xor(sB1, off, 64);
        sB2 += __shfl_xor(sB2, off, 64);
    }
    float muA = sA1 * (1.f / 128.f);
    float varA = fmaxf(sA2 * (1.f / 128.f) - muA * muA, 0.f);
    float rsA = rsqrtf(varA + LN_EPS);
    float muB = sB1 * (1.f / 128.f);
    float varB = fmaxf(sB2 * (1.f / 128.f) - muB * muB, 0.f);
    float rsB = rsqrtf(varB + LN_EPS);

    float oA0 = (vA0 - muA) * rsA * gv.x + bt.x;
    float oA1 = (vA1 - muA) * rsA * gv.y + bt.y;
    float oB0 = (vB0 - muB) * rsB * gv.x + bt.x;
    float oB1 = (vB1 - muB) * rsB * gv.y + bt.y;

    int rA = wid * 2, rB = wid * 2 + 1;
    unsigned dwA = (unsigned)f2bf(oA0) | ((unsigned)f2bf(oA1) << 16);
    unsigned dwB = (unsigned)f2bf(oB0) | ((unsigned)f2bf(oB1) << 16);
    int byteA = (rA * 256 + lane * 4) ^ ((rA & 7) << 4);
    int byteB = (rB * 256 + lane * 4) ^ ((rB & 7) << 4);
    *(unsigned*)((char*)a_lds + byteA) = dwA;
    *(unsigned*)((char*)a_lds + byteB) = dwB;
    __syncthreads();

    int lrow = lane & 15, lgrp = lane >> 4;
    f32x4 acc = (f32x4){0.f, 0.f, 0.f, 0.f};
    #pragma unroll
    for (int kk = 0; kk < 4; ++kk) {
        int abyte = (lrow * 256 + kk * 64 + lgrp * 16) ^ ((lrow & 7) << 4);
        bf16x8 afrag = *(bf16x8*)((char*)a_lds + abyte);
        int bcol = wid * 16 + lrow;
        int bbyte = (bcol * 256 + kk * 64 + lgrp * 16) ^ ((bcol & 7) << 4);
        bf16x8 bfrag = *(bf16x8*)((char*)w_lds + bbyte);
        acc = __builtin_amdgcn_mfma_f32_16x16x32_bf16(afrag, bfrag, acc, 0, 0, 0);
    }
    #pragma unroll
    for (int r = 0; r < 4; ++r) {
        int grow = blockIdx.x * 16 + lgrp * 4 + r;
        hbf2[(size_t)grow * D + wid * 16 + lrow] = f2bf(dinv[grow] * acc[r]);
    }
}

// ---------------- layer 2: agg + bias + residual + LN2 + leaky (final f32 out) ----------------
__global__ __launch_bounds__(256) void agg_ln2(const unsigned* __restrict__ h,
                                               const float* __restrict__ x,
                                               const float* __restrict__ bias,
                                               const float* __restrict__ gamma,
                                               const float* __restrict__ beta,
                                               const float* __restrict__ dinv,
                                               const int2* __restrict__ rowinfo,
                                               const int* __restrict__ csr_src,
                                               float* __restrict__ out) {
    int wid = threadIdx.x >> 6;
    int lane = threadIdx.x & 63;
    int iA = blockIdx.x * 8 + wid * 2;   // NN = 50000 = 6250 * 8, exact
    int iB = iA + 1;
    float diA = dinv[iA], diB = dinv[iB];

    float aAx, aAy, aBx, aBy;
    bf2x(h[(size_t)iA * (D / 2) + lane], aAx, aAy);
    bf2x(h[(size_t)iB * (D / 2) + lane], aBx, aBy);

    int2 riA = rowinfo[iA];
    int2 riB = rowinfo[iB];
    int eA = __builtin_amdgcn_readfirstlane(riA.x);
    int eA1 = eA + __builtin_amdgcn_readfirstlane(riA.y);
    int eB = __builtin_amdgcn_readfirstlane(riB.x);
    int eB1 = eB + __builtin_amdgcn_readfirstlane(riB.y);
    agg_2node(h, csr_src, eA, eA1, eB, eB1, lane, aAx, aAy, aBx, aBy);

    float2 bv = *(const float2*)&bias[2 * lane];
    float2 gv = *(const float2*)&gamma[2 * lane];
    float2 bt = *(const float2*)&beta[2 * lane];

    aAx = fmaf(diA, aAx, bv.x); aAy = fmaf(diA, aAy, bv.y);
    aBx = fmaf(diB, aBx, bv.x); aBy = fmaf(diB, aBy, bv.y);
    size_t rowA = (size_t)iA * D + 2 * lane;
    size_t rowB = (size_t)iB * D + 2 * lane;
    float2 xA = *(const float2*)&x[rowA];
    float2 xB = *(const float2*)&x[rowB];
    float vA0 = aAx + xA.x, vA1 = aAy + xA.y;
    float vB0 = aBx + xB.x, vB1 = aBy + xB.y;

    float sA1 = vA0 + vA1, sA2 = vA0 * vA0 + vA1 * vA1;
    float sB1 = vB0 + vB1, sB2 = vB0 * vB0 + vB1 * vB1;
    #pragma unroll
    for (int off = 1; off < 64; off <<= 1) {
        sA1 += __shfl_xor(sA1, off, 64);
        sA2 += __shfl_xor(sA2, off, 64);
        sB1 += __shfl_xor(sB1, off, 64);
        sB2 += __shfl_xor(sB2, off, 64);
    }
    float muA = sA1 * (1.f / 128.f);
    float varA = fmaxf(sA2 * (1.f / 128.f) - muA * muA, 0.f);
    float rsA = rsqrtf(varA + LN_EPS);
    float muB = sB1 * (1.f / 128.f);
    float varB = fmaxf(sB2 * (1.f / 128.f) - muB * muB, 0.f);
    float rsB = rsqrtf(varB + LN_EPS);

    float oA0 = (vA0 - muA) * rsA * gv.x + bt.x;
    float oA1 = (vA1 - muA) * rsA * gv.y + bt.y;
    float oB0 = (vB0 - muB) * rsB * gv.x + bt.x;
    float oB1 = (vB1 - muB) * rsB * gv.y + bt.y;
    oA0 = oA0 > 0.f ? oA0 : NEG_SLOPE * oA0;
    oA1 = oA1 > 0.f ? oA1 : NEG_SLOPE * oA1;
    oB0 = oB0 > 0.f ? oB0 : NEG_SLOPE * oB0;
    oB1 = oB1 > 0.f ? oB1 : NEG_SLOPE * oB1;
    *(float2*)&out[rowA] = make_float2(oA0, oA1);
    *(float2*)&out[rowB] = make_float2(oB0, oB1);
}

extern "C" void kernel_launch(void* const* d_in, const int* in_sizes, int n_in,
                              void* d_out, int out_size, void* d_ws, size_t ws_size,
                              hipStream_t stream) {
    const float* x    = (const float*)d_in[0];
    const int*   ei   = (const int*)d_in[1];   // [2, NE]: row0 src, row1 dst
    const float* W1   = (const float*)d_in[2];
    const float* b1   = (const float*)d_in[3];
    const float* ln1g = (const float*)d_in[4];
    const float* ln1b = (const float*)d_in[5];
    const float* W2   = (const float*)d_in[6];
    const float* b2   = (const float*)d_in[7];
    const float* ln2g = (const float*)d_in[8];
    const float* ln2b = (const float*)d_in[9];
    float* out = (float*)d_out;

    const int* srcp = ei;
    const int* dstp = ei + NE;

    char* ws = (char*)d_ws;
    size_t p = 0;
    auto alloc = [&](size_t bytes) {
        char* r = ws + p;
        p += (bytes + 255) & ~(size_t)255;
        return r;
    };
    int*   bcursor  = (int*)alloc((NB + 1) * 4);         // [NB] = ticket
    int2*  rowinfo  = (int2*)alloc((size_t)NN * 8);
    float* dinv     = (float*)alloc(NN * 4);
    int2*  bedge    = (int2*)alloc((size_t)NB * CAP * 8);
    int*   csr_src  = (int*)alloc(((size_t)NE + 8 * NN) * 4);  // padded CSR, 4 B/edge
    unsigned short* hbf  = (unsigned short*)alloc((size_t)(NN + 8) * D * 2);  // +zero row
    unsigned short* hbf2 = (unsigned short*)alloc((size_t)(NN + 8) * D * 2);  // +zero row
    unsigned short* wt1  = (unsigned short*)alloc(D * D * 2);
    unsigned short* wt2  = (unsigned short*)alloc(D * D * 2);

    hipMemsetAsync(bcursor, 0, (NB + 1) * 4, stream);

    // bucket scatter || weight pack (+ zero pad rows)
    fused_a<<<NCH + NWPK, 256, 0, stream>>>(srcp, dstp, bcursor, bedge,
                                            W1, W2, wt1, wt2, hbf, hbf2);

    // per-bucket: histogram -> dinv/rowinfo -> padded CSR
    fused_b<<<NB, 256, 0, stream>>>(bedge, bcursor, dinv, rowinfo,
                                    &bcursor[NB], csr_src);

    // GEMM1: hbf = dinv ⊙ bf16(x @ W1)
    gemm_mfma<<<(NN + 63) / 64, 256, 0, stream>>>(x, wt1, dinv, hbf, NN);

    // Layer 1 (+ fused GEMM2): hbf2 = dinv ⊙ ( LN1(leaky(agg(hbf)+b1)+x) @ W2 )
    agg_ln1_gemm<<<NN / 16, 512, 0, stream>>>((const unsigned*)hbf, x, b1, ln1g, ln1b,
                                              dinv, rowinfo, csr_src, wt2, hbf2);

    // Layer 2: out = leaky(LN2(agg(hbf2)+b2+x))
    agg_ln2<<<NN / 8, 256, 0, stream>>>((const unsigned*)hbf2, x, b2, ln2g, ln2b,
                                        dinv, rowinfo, csr_src, out);
}